// Round 9
// baseline (151.964 us; speedup 1.0000x reference)
//
#include <hip/hip_runtime.h>
#include <hip/hip_bf16.h>
#include <math.h>

// bucket = 64 consecutive dst nodes. key packs (dlow<<17 | src), valid for n < 131072.
#define BSHIFT 6
#define BNODES 64
#define MAXB 1024   // max buckets supported by in-block scan (n <= 65536)
#define SORTCAP 4096
#define TILE 16     // edges cached in registers per thread in k_binscatter

// ---------------- inline dtype detection: int64 vs int32 edge_index ----------------
__device__ __forceinline__ bool detect_f64(const void* edges, long long nn) {
    const long long* e64 = (const long long*)edges;
    bool ok = true;
#pragma unroll
    for (int i = 0; i < 8; ++i) {
        long long v = e64[i];
        ok = ok && (v >= 0 && v < nn);
    }
    return ok;
}

__device__ __forceinline__ float bf16lo(unsigned int u) {
    return __uint_as_float(u << 16);
}
__device__ __forceinline__ float bf16hi(unsigned int u) {
    return __uint_as_float(u & 0xFFFF0000u);
}
__device__ __forceinline__ float bf16dec(unsigned short u) {
    return __uint_as_float(((unsigned int)u) << 16);
}
__device__ __forceinline__ unsigned short bf16enc(float f) {
    __hip_bfloat16 h = __float2bfloat16(f);
    return *reinterpret_cast<unsigned short*>(&h);
}

// ------- per-bucket edge counts + fused exclusive scan (last block finishes) -------
// totals[nbuckets] doubles as the done-ticket counter (memset to 0 with totals).
__global__ __launch_bounds__(512) void k_buckcount(const void* edges, long long nn,
                                                   long long E, int nbuckets, int* totals,
                                                   int* base, int* cursor) {
    __shared__ int cnt[MAXB];
    __shared__ int tmp[512];
    __shared__ int lastflag;
    int t = threadIdx.x;
    for (int b = t; b < nbuckets; b += 512) cnt[b] = 0;
    __syncthreads();
    bool f64 = detect_f64(edges, nn);
    long long chunk = (E + gridDim.x - 1) / gridDim.x;
    long long e0 = (long long)blockIdx.x * chunk;
    long long e1 = e0 + chunk; if (e1 > E) e1 = E;
    for (long long e = e0 + t; e < e1; e += 512) {
        int d = f64 ? (int)((const long long*)edges)[E + e] : ((const int*)edges)[E + e];
        atomicAdd(&cnt[d >> BSHIFT], 1);
    }
    __syncthreads();
    for (int b = t; b < nbuckets; b += 512)
        if (cnt[b] > 0) atomicAdd(&totals[b], cnt[b]);
    __threadfence();
    if (t == 0) {
        int r = atomicAdd(&totals[nbuckets], 1);
        lastflag = (r == (int)gridDim.x - 1);
    }
    __syncthreads();
    if (!lastflag) return;
    // last block: exclusive scan of totals[0..nbuckets) -> base, cursor
    int i0 = 2 * t, i1 = 2 * t + 1;
    int a0 = (i0 < nbuckets) ? atomicAdd(&totals[i0], 0) : 0;  // coherent read
    int a1 = (i1 < nbuckets) ? atomicAdd(&totals[i1], 0) : 0;
    tmp[t] = a0 + a1;
    __syncthreads();
    for (int off = 1; off < 512; off <<= 1) {
        int a = (t >= off) ? tmp[t - off] : 0;
        __syncthreads();
        tmp[t] += a;
        __syncthreads();
    }
    int ex = tmp[t] - (a0 + a1);
    if (i0 < nbuckets) { base[i0] = ex; cursor[i0] = ex; }
    if (i1 < nbuckets) { base[i1] = ex + a0; cursor[i1] = ex + a0; }
}

// ------- bin edges into bucket-major key array (single edge read, reg-cached) -------
__global__ __launch_bounds__(512) void k_binscatter(const void* edges, long long nn,
                                                    long long E, int nbuckets, int* cursor,
                                                    unsigned int* keys) {
    __shared__ int cnt[MAXB];
    __shared__ int base_l[MAXB];
    int t = threadIdx.x;
    bool f64 = detect_f64(edges, nn);
    long long chunk = (E + gridDim.x - 1) / gridDim.x;
    long long e0 = (long long)blockIdx.x * chunk;
    long long e1 = e0 + chunk; if (e1 > E) e1 = E;
    for (long long tile0 = e0; tile0 < e1; tile0 += (long long)512 * TILE) {
        for (int b = t; b < nbuckets; b += 512) cnt[b] = 0;
        __syncthreads();
        int ss[TILE], dd[TILE];
        // pass 1: load once into registers + LDS histogram
#pragma unroll
        for (int j = 0; j < TILE; ++j) {
            long long e = tile0 + (long long)j * 512 + t;
            int s = 0, d = -1;
            if (e < e1) {
                if (f64) {
                    const long long* ee = (const long long*)edges;
                    s = (int)ee[e]; d = (int)ee[E + e];
                } else {
                    const int* ee = (const int*)edges;
                    s = ee[e]; d = ee[E + e];
                }
                atomicAdd(&cnt[d >> BSHIFT], 1);
            }
            ss[j] = s; dd[j] = d;
        }
        __syncthreads();
        // claim contiguous chunks per bucket
        for (int b = t; b < nbuckets; b += 512) {
            int c = cnt[b];
            base_l[b] = (c > 0) ? atomicAdd(&cursor[b], c) : 0;
            cnt[b] = 0;
        }
        __syncthreads();
        // pass 2: place keys from registers
#pragma unroll
        for (int j = 0; j < TILE; ++j) {
            int d = dd[j];
            if (d >= 0) {
                int b = d >> BSHIFT;
                int pos = base_l[b] + atomicAdd(&cnt[b], 1);
                keys[pos] = (unsigned int)ss[j] | ((unsigned int)(d & (BNODES - 1)) << 17);
            }
        }
        __syncthreads();
    }
}

// -------- per-bucket LDS counting sort -> node-exact CSR; fuses deg/dinv --------
__global__ __launch_bounds__(256) void k_sortdeg(unsigned int* keys,
                                                 const int* __restrict__ base,
                                                 const int* __restrict__ totals,
                                                 int* rowstart, int* counts,
                                                 float* dinv, int n,
                                                 unsigned int* scratch) {
    __shared__ unsigned int kbuf[SORTCAP];
    __shared__ int hist[BNODES];
    __shared__ int cur[BNODES];
    int t = threadIdx.x;
    int bk = blockIdx.x;
    int st = base[bk], c = totals[bk];
    if (t < BNODES) hist[t] = 0;
    __syncthreads();
    bool fits = (c <= SORTCAP);
    if (fits) {
        for (int i = t; i < c; i += 256) {
            unsigned int k = keys[st + i];
            kbuf[i] = k;
            atomicAdd(&hist[k >> 17], 1);
        }
    } else {  // statistically never for random edges; correct fallback via global scratch
        for (int i = t; i < c; i += 256) {
            unsigned int k = keys[st + i];
            scratch[st + i] = k;
            atomicAdd(&hist[k >> 17], 1);
        }
    }
    __syncthreads();
    if (t < 64) {  // wave 0: scan 64 counters
        int v = hist[t];
        int incl = v;
        for (int o = 1; o < 64; o <<= 1) {
            int other = __shfl_up(incl, o, 64);
            if (t >= o) incl += other;
        }
        int ex = incl - v;
        cur[t] = ex;
        int node = bk * BNODES + t;
        if (node < n) {
            rowstart[node] = st + ex;
            counts[node] = v;
            dinv[node] = rsqrtf((float)v + 1.0f);
        }
    }
    __syncthreads();
    if (fits) {
        for (int i = t; i < c; i += 256) {
            unsigned int k = kbuf[i];
            int pos = atomicAdd(&cur[k >> 17], 1);
            keys[st + pos] = k & 0x1FFFFu;
        }
    } else {
        for (int i = t; i < c; i += 256) {
            unsigned int k = scratch[st + i];
            int pos = atomicAdd(&cur[k >> 17], 1);
            keys[st + pos] = k & 0x1FFFFu;
        }
    }
}

// -------- GEMM1: h1b[n,64](bf16) = dinv * (x[n,64] @ W1[64,64]) --------
__global__ __launch_bounds__(256) void k_gemm1(const float* __restrict__ x,
                                               const float* __restrict__ W,
                                               const float* __restrict__ dinv,
                                               unsigned short* __restrict__ h) {
    __shared__ float Ws[64][64];
    __shared__ float xs[16][64];
    int t = threadIdx.x;
    for (int i = t; i < 64 * 64; i += 256) Ws[i >> 6][i & 63] = W[i];
    long long row0 = (long long)blockIdx.x * 16;
    ((float4*)xs)[t] = ((const float4*)(x + row0 * 64))[t];
    __syncthreads();
    int r = t >> 4, c0 = (t & 15) * 4;
    float4 acc = {0.f, 0.f, 0.f, 0.f};
#pragma unroll
    for (int k = 0; k < 64; ++k) {
        float xv = xs[r][k];
        float4 wv = *((const float4*)&Ws[k][c0]);
        acc.x += xv * wv.x; acc.y += xv * wv.y;
        acc.z += xv * wv.z; acc.w += xv * wv.w;
    }
    float di = dinv[row0 + r];
    ushort4 pk;
    pk.x = bf16enc(di * acc.x);
    pk.y = bf16enc(di * acc.y);
    pk.z = bf16enc(di * acc.z);
    pk.w = bf16enc(di * acc.w);
    *((ushort4*)(h + (row0 + r) * 64 + c0)) = pk;
}

// ------- GEMM2: h2b[n,16](bf16) = dinv * (out1b[n,64](bf16) @ W2[64,16]) -------
__global__ __launch_bounds__(256) void k_gemm2(const unsigned short* __restrict__ h,
                                               const float* __restrict__ W,
                                               const float* __restrict__ dinv,
                                               unsigned short* __restrict__ h2) {
    __shared__ float Ws[64 * 16];
    __shared__ float xs[16][64];
    int t = threadIdx.x;
    for (int i = t; i < 64 * 16; i += 256) Ws[i] = W[i];
    long long row0 = (long long)blockIdx.x * 16;
    ushort4 u4 = ((const ushort4*)(h + row0 * 64))[t];
    int lr = t >> 4, lc = (t & 15) * 4;
    xs[lr][lc + 0] = bf16dec(u4.x);
    xs[lr][lc + 1] = bf16dec(u4.y);
    xs[lr][lc + 2] = bf16dec(u4.z);
    xs[lr][lc + 3] = bf16dec(u4.w);
    __syncthreads();
    int r = t >> 4, c = t & 15;
    float acc = 0.f;
#pragma unroll
    for (int k = 0; k < 64; ++k) acc += xs[r][k] * Ws[k * 16 + c];
    h2[(row0 + r) * 16 + c] = bf16enc(dinv[row0 + r] * acc);
}

// ------- CSR aggregation, 64 feats (bf16, 4-wide): wave per node ----------------
// 16 lanes x uint2 cover a 128B row; quarter-waves take edges k+0..k+3.
__global__ __launch_bounds__(256) void k_agg64(const int* __restrict__ rowstart,
                                               const int* __restrict__ counts,
                                               const unsigned int* __restrict__ srcs,
                                               const uint2* __restrict__ hb4,
                                               const float* __restrict__ dinv,
                                               const float* __restrict__ b,
                                               unsigned short* __restrict__ out, int n) {
    int d = (blockIdx.x * 256 + threadIdx.x) >> 6;
    if (d >= n) return;
    int lane = threadIdx.x & 63;
    int q = lane >> 4;        // quarter: edge offset 0..3
    int fl = lane & 15;       // feature-quad index (feats 4fl..4fl+3)
    float a0 = 0.f, a1 = 0.f, a2 = 0.f, a3 = 0.f;
    if (q == 0) {             // self-loop counted once
        uint2 u = hb4[(long long)d * 16 + fl];
        a0 = bf16lo(u.x); a1 = bf16hi(u.x); a2 = bf16lo(u.y); a3 = bf16hi(u.y);
    }
    int start = rowstart[d];
    int cnt = counts[d];
    int k = 0;
    for (; k + 16 <= cnt; k += 16) {
        unsigned int s0 = srcs[start + k + q];
        unsigned int s1 = srcs[start + k + 4 + q];
        unsigned int s2 = srcs[start + k + 8 + q];
        unsigned int s3 = srcs[start + k + 12 + q];
        uint2 u0 = hb4[(long long)s0 * 16 + fl];
        uint2 u1 = hb4[(long long)s1 * 16 + fl];
        uint2 u2 = hb4[(long long)s2 * 16 + fl];
        uint2 u3 = hb4[(long long)s3 * 16 + fl];
        a0 += bf16lo(u0.x); a1 += bf16hi(u0.x); a2 += bf16lo(u0.y); a3 += bf16hi(u0.y);
        a0 += bf16lo(u1.x); a1 += bf16hi(u1.x); a2 += bf16lo(u1.y); a3 += bf16hi(u1.y);
        a0 += bf16lo(u2.x); a1 += bf16hi(u2.x); a2 += bf16lo(u2.y); a3 += bf16hi(u2.y);
        a0 += bf16lo(u3.x); a1 += bf16hi(u3.x); a2 += bf16lo(u3.y); a3 += bf16hi(u3.y);
    }
    for (; k < cnt; k += 4) {
        int idx = k + q;
        if (idx < cnt) {
            uint2 u = hb4[(long long)srcs[start + idx] * 16 + fl];
            a0 += bf16lo(u.x); a1 += bf16hi(u.x); a2 += bf16lo(u.y); a3 += bf16hi(u.y);
        }
    }
    // combine quarters (lane^16, lane^32 hold same fl)
    a0 += __shfl_xor(a0, 16); a0 += __shfl_xor(a0, 32);
    a1 += __shfl_xor(a1, 16); a1 += __shfl_xor(a1, 32);
    a2 += __shfl_xor(a2, 16); a2 += __shfl_xor(a2, 32);
    a3 += __shfl_xor(a3, 16); a3 += __shfl_xor(a3, 32);
    if (q == 0) {
        float di = dinv[d];
        float4 bb = ((const float4*)b)[fl];
        float o0 = fmaxf(di * a0 + bb.x, 0.f);
        float o1 = fmaxf(di * a1 + bb.y, 0.f);
        float o2 = fmaxf(di * a2 + bb.z, 0.f);
        float o3 = fmaxf(di * a3 + bb.w, 0.f);
        uint2 pk;
        pk.x = (unsigned int)bf16enc(o0) | ((unsigned int)bf16enc(o1) << 16);
        pk.y = (unsigned int)bf16enc(o2) | ((unsigned int)bf16enc(o3) << 16);
        ((uint2*)(out + (long long)d * 64))[fl] = pk;
    }
}

// ------- CSR aggregation, 16 feats (bf16, 2-wide) + fused log_softmax -----------
// 8 lanes x uint cover a 32B row; 16-lane group = 2 halves taking edges k+0,k+1.
__global__ __launch_bounds__(256) void k_agg16(const int* __restrict__ rowstart,
                                               const int* __restrict__ counts,
                                               const unsigned int* __restrict__ srcs,
                                               const unsigned int* __restrict__ hb2,
                                               const float* __restrict__ dinv,
                                               const float* __restrict__ b,
                                               float* __restrict__ out, int n) {
    int g = (blockIdx.x * 256 + threadIdx.x) >> 4;
    if (g >= n) return;
    int lane = threadIdx.x & 15;
    int h = lane >> 3;        // half: edge offset 0..1
    int f8 = lane & 7;        // feature-pair index (feats 2f8, 2f8+1)
    float ax = 0.f, ay = 0.f;
    if (h == 0) {
        unsigned int u = hb2[(long long)g * 8 + f8];
        ax = bf16lo(u); ay = bf16hi(u);
    }
    int start = rowstart[g];
    int cnt = counts[g];
    int k = 0;
    for (; k + 8 <= cnt; k += 8) {
        unsigned int s0 = srcs[start + k + h];
        unsigned int s1 = srcs[start + k + 2 + h];
        unsigned int s2 = srcs[start + k + 4 + h];
        unsigned int s3 = srcs[start + k + 6 + h];
        unsigned int u0 = hb2[(long long)s0 * 8 + f8];
        unsigned int u1 = hb2[(long long)s1 * 8 + f8];
        unsigned int u2 = hb2[(long long)s2 * 8 + f8];
        unsigned int u3 = hb2[(long long)s3 * 8 + f8];
        ax += bf16lo(u0); ay += bf16hi(u0);
        ax += bf16lo(u1); ay += bf16hi(u1);
        ax += bf16lo(u2); ay += bf16hi(u2);
        ax += bf16lo(u3); ay += bf16hi(u3);
    }
    for (; k < cnt; k += 2) {
        int idx = k + h;
        if (idx < cnt) {
            unsigned int u = hb2[(long long)srcs[start + idx] * 8 + f8];
            ax += bf16lo(u); ay += bf16hi(u);
        }
    }
    ax += __shfl_xor(ax, 8);  // combine halves; both halves now hold totals
    ay += __shfl_xor(ay, 8);
    float di = dinv[g];
    float2 bb = ((const float2*)b)[f8];
    float v0 = di * ax + bb.x;
    float v1 = di * ay + bb.y;
    float m = fmaxf(v0, v1);
#pragma unroll
    for (int o = 4; o >= 1; o >>= 1) m = fmaxf(m, __shfl_xor(m, o));
    float ex = __expf(v0 - m) + __expf(v1 - m);
#pragma unroll
    for (int o = 4; o >= 1; o >>= 1) ex += __shfl_xor(ex, o);
    float lse = __logf(ex);
    if (h == 0) {
        float2 o2;
        o2.x = (v0 - m) - lse;
        o2.y = (v1 - m) - lse;
        ((float2*)(out + (long long)g * 16))[f8] = o2;
    }
}

extern "C" void kernel_launch(void* const* d_in, const int* in_sizes, int n_in,
                              void* d_out, int out_size, void* d_ws, size_t ws_size,
                              hipStream_t stream) {
    const float* x  = (const float*)d_in[0];
    const void*  ei = d_in[1];
    const float* W1 = (const float*)d_in[2];
    const float* b1 = (const float*)d_in[3];
    const float* W2 = (const float*)d_in[4];
    const float* b2 = (const float*)d_in[5];

    long long dh  = in_sizes[3];                 // 64
    long long din = in_sizes[2] / dh;            // 64
    long long n   = in_sizes[0] / din;           // 50000
    long long E   = (long long)in_sizes[1] / 2;  // 1.6M
    int nbuckets  = (int)((n + BNODES - 1) >> BSHIFT);  // 782

    char* ws = (char*)d_ws;
    auto alloc = [&](size_t bytes) { void* p = ws; ws += (bytes + 255) & ~255ULL; return p; };
    int*   totals   = (int*)alloc((nbuckets + 1) * 4);  // +1: done-ticket counter
    int*   base     = (int*)alloc(nbuckets * 4);
    int*   cursor   = (int*)alloc(nbuckets * 4);
    int*   rowstart = (int*)alloc(n * 4);
    int*   counts   = (int*)alloc(n * 4);
    float* dinv     = (float*)alloc(n * 4);
    unsigned int* keys = (unsigned int*)alloc(E * 4);
    unsigned short* h1b  = (unsigned short*)alloc(n * 64 * 2);
    unsigned short* out1 = (unsigned short*)alloc(n * 64 * 2);
    unsigned short* h2b  = (unsigned short*)alloc(n * 16 * 2);
    // out1 written only after sortdeg completes; before then its space doubles
    // as the (statistically never used) big-bucket sort scratch (E*4 <= n*64*2).
    unsigned int* sort_scratch = (unsigned int*)out1;

    float* out = (float*)d_out;

    hipMemsetAsync(totals, 0, (size_t)(nbuckets + 1) * 4, stream);

    k_buckcount<<<256, 512, 0, stream>>>(ei, n, E, nbuckets, totals, base, cursor);
    k_binscatter<<<256, 512, 0, stream>>>(ei, n, E, nbuckets, cursor, keys);
    k_sortdeg<<<nbuckets, 256, 0, stream>>>(keys, base, totals, rowstart, counts,
                                            dinv, (int)n, sort_scratch);

    // layer 1
    k_gemm1<<<(int)(n / 16), 256, 0, stream>>>(x, W1, dinv, h1b);
    k_agg64<<<(int)((n * 64 + 255) / 256), 256, 0, stream>>>(
        rowstart, counts, keys, (const uint2*)h1b, dinv, b1, out1, (int)n);

    // layer 2
    k_gemm2<<<(int)(n / 16), 256, 0, stream>>>(out1, W2, dinv, h2b);
    k_agg16<<<(int)((n * 16 + 255) / 256), 256, 0, stream>>>(
        rowstart, counts, keys, (const unsigned int*)h2b, dinv, b2, out, (int)n);
}

// Round 10
// 123.735 us; speedup vs baseline: 1.2281x; 1.2281x over previous
//
#include <hip/hip_runtime.h>
#include <hip/hip_bf16.h>
#include <math.h>

// bucket = 64 consecutive dst nodes. key packs (dlow<<17 | src), valid for n < 131072.
#define BSHIFT 6
#define BNODES 64
#define MAXB 1024   // max buckets supported by single-block scan (n <= 65536)
#define SORTCAP 4096

// ---------------- inline dtype detection: int64 vs int32 edge_index ----------------
__device__ __forceinline__ bool detect_f64(const void* edges, long long nn) {
    const long long* e64 = (const long long*)edges;
    bool ok = true;
#pragma unroll
    for (int i = 0; i < 8; ++i) {
        long long v = e64[i];
        ok = ok && (v >= 0 && v < nn);
    }
    return ok;
}

__device__ __forceinline__ float bf16lo(unsigned int u) {
    return __uint_as_float(u << 16);
}
__device__ __forceinline__ float bf16hi(unsigned int u) {
    return __uint_as_float(u & 0xFFFF0000u);
}
__device__ __forceinline__ float bf16dec(unsigned short u) {
    return __uint_as_float(((unsigned int)u) << 16);
}
__device__ __forceinline__ unsigned short bf16enc(float f) {
    __hip_bfloat16 h = __float2bfloat16(f);
    return *reinterpret_cast<unsigned short*>(&h);
}

// ---- (A) per-block-slice histogram -> partial[b*nblk + i] (plain stores) ----
__global__ __launch_bounds__(512) void k_hist(const void* edges, long long nn,
                                              long long E, long long epb,
                                              int nbuckets, int nblk, int* partial) {
    __shared__ int cnt[MAXB];
    int t = threadIdx.x;
    int i = blockIdx.x;
    for (int b = t; b < nbuckets; b += 512) cnt[b] = 0;
    __syncthreads();
    bool f64 = detect_f64(edges, nn);
    long long e0 = (long long)i * epb;
    long long e1 = e0 + epb; if (e1 > E) e1 = E;
    for (long long e = e0 + t; e < e1; e += 512) {
        int d = f64 ? (int)((const long long*)edges)[E + e] : ((const int*)edges)[E + e];
        atomicAdd(&cnt[d >> BSHIFT], 1);
    }
    __syncthreads();
    for (int b = t; b < nbuckets; b += 512) partial[b * nblk + i] = cnt[b];
}

// ---- (B) per-bucket exclusive scan over blocks; emits bucket totals ----
__global__ __launch_bounds__(256) void k_scanB(int* partial, int nblk, int* totals) {
    __shared__ int tmp[256];
    int b = blockIdx.x, t = threadIdx.x;
    int v = (t < nblk) ? partial[b * nblk + t] : 0;
    tmp[t] = v;
    __syncthreads();
    for (int off = 1; off < 256; off <<= 1) {
        int a = (t >= off) ? tmp[t - off] : 0;
        __syncthreads();
        tmp[t] += a;
        __syncthreads();
    }
    if (t < nblk) partial[b * nblk + t] = tmp[t] - v;  // exclusive over blocks
    if (t == 255) totals[b] = tmp[255];
}

// ---- (C) bucket-level exclusive scan: base = exclusive(totals) ----
__global__ __launch_bounds__(1024) void k_scan(const int* __restrict__ totals, int nbuckets,
                                               int* base) {
    __shared__ int tmp[MAXB];
    int t = threadIdx.x;
    int v = (t < nbuckets) ? totals[t] : 0;
    tmp[t] = v;
    __syncthreads();
    for (int off = 1; off < MAXB; off <<= 1) {
        int a = (t >= off) ? tmp[t - off] : 0;
        __syncthreads();
        tmp[t] += a;
        __syncthreads();
    }
    if (t < nbuckets) base[t] = tmp[t] - v;
}

// ---- (D) place keys: LDS cursors seeded from base+partial; no global atomics ----
__global__ __launch_bounds__(512) void k_place(const void* edges, long long nn,
                                               long long E, long long epb,
                                               int nbuckets, int nblk,
                                               const int* __restrict__ base,
                                               const int* __restrict__ partial,
                                               unsigned int* keys) {
    __shared__ int cur[MAXB];
    int t = threadIdx.x;
    int i = blockIdx.x;
    for (int b = t; b < nbuckets; b += 512) cur[b] = base[b] + partial[b * nblk + i];
    __syncthreads();
    bool f64 = detect_f64(edges, nn);
    long long e0 = (long long)i * epb;
    long long e1 = e0 + epb; if (e1 > E) e1 = E;
    for (long long e = e0 + t; e < e1; e += 512) {
        int s, d;
        if (f64) {
            const long long* ee = (const long long*)edges;
            s = (int)ee[e]; d = (int)ee[E + e];
        } else {
            const int* ee = (const int*)edges;
            s = ee[e]; d = ee[E + e];
        }
        int pos = atomicAdd(&cur[d >> BSHIFT], 1);
        keys[pos] = (unsigned int)s | ((unsigned int)(d & (BNODES - 1)) << 17);
    }
}

// -------- per-bucket LDS counting sort -> node-exact CSR; fuses deg/dinv --------
__global__ __launch_bounds__(256) void k_sortdeg(unsigned int* keys,
                                                 const int* __restrict__ base,
                                                 const int* __restrict__ totals,
                                                 int* rowstart, int* counts,
                                                 float* dinv, int n,
                                                 unsigned int* scratch) {
    __shared__ unsigned int kbuf[SORTCAP];
    __shared__ int hist[BNODES];
    __shared__ int cur[BNODES];
    int t = threadIdx.x;
    int bk = blockIdx.x;
    int st = base[bk], c = totals[bk];
    if (t < BNODES) hist[t] = 0;
    __syncthreads();
    bool fits = (c <= SORTCAP);
    if (fits) {
        for (int i = t; i < c; i += 256) {
            unsigned int k = keys[st + i];
            kbuf[i] = k;
            atomicAdd(&hist[k >> 17], 1);
        }
    } else {  // statistically never for random edges; correct fallback via global scratch
        for (int i = t; i < c; i += 256) {
            unsigned int k = keys[st + i];
            scratch[st + i] = k;
            atomicAdd(&hist[k >> 17], 1);
        }
    }
    __syncthreads();
    if (t < 64) {  // wave 0: scan 64 counters
        int v = hist[t];
        int incl = v;
        for (int o = 1; o < 64; o <<= 1) {
            int other = __shfl_up(incl, o, 64);
            if (t >= o) incl += other;
        }
        int ex = incl - v;
        cur[t] = ex;
        int node = bk * BNODES + t;
        if (node < n) {
            rowstart[node] = st + ex;
            counts[node] = v;
            dinv[node] = rsqrtf((float)v + 1.0f);
        }
    }
    __syncthreads();
    if (fits) {
        for (int i = t; i < c; i += 256) {
            unsigned int k = kbuf[i];
            int pos = atomicAdd(&cur[k >> 17], 1);
            keys[st + pos] = k & 0x1FFFFu;
        }
    } else {
        for (int i = t; i < c; i += 256) {
            unsigned int k = scratch[st + i];
            int pos = atomicAdd(&cur[k >> 17], 1);
            keys[st + pos] = k & 0x1FFFFu;
        }
    }
}

// -------- GEMM1: h1b[n,64](bf16) = dinv * (x[n,64] @ W1[64,64]) --------
__global__ __launch_bounds__(256) void k_gemm1(const float* __restrict__ x,
                                               const float* __restrict__ W,
                                               const float* __restrict__ dinv,
                                               unsigned short* __restrict__ h) {
    __shared__ float Ws[64][64];
    __shared__ float xs[16][64];
    int t = threadIdx.x;
    for (int i = t; i < 64 * 64; i += 256) Ws[i >> 6][i & 63] = W[i];
    long long row0 = (long long)blockIdx.x * 16;
    ((float4*)xs)[t] = ((const float4*)(x + row0 * 64))[t];
    __syncthreads();
    int r = t >> 4, c0 = (t & 15) * 4;
    float4 acc = {0.f, 0.f, 0.f, 0.f};
#pragma unroll
    for (int k = 0; k < 64; ++k) {
        float xv = xs[r][k];
        float4 wv = *((const float4*)&Ws[k][c0]);
        acc.x += xv * wv.x; acc.y += xv * wv.y;
        acc.z += xv * wv.z; acc.w += xv * wv.w;
    }
    float di = dinv[row0 + r];
    ushort4 pk;
    pk.x = bf16enc(di * acc.x);
    pk.y = bf16enc(di * acc.y);
    pk.z = bf16enc(di * acc.z);
    pk.w = bf16enc(di * acc.w);
    *((ushort4*)(h + (row0 + r) * 64 + c0)) = pk;
}

// ------- GEMM2: h2b[n,16](bf16) = dinv * (out1b[n,64](bf16) @ W2[64,16]) -------
__global__ __launch_bounds__(256) void k_gemm2(const unsigned short* __restrict__ h,
                                               const float* __restrict__ W,
                                               const float* __restrict__ dinv,
                                               unsigned short* __restrict__ h2) {
    __shared__ float Ws[64 * 16];
    __shared__ float xs[16][64];
    int t = threadIdx.x;
    for (int i = t; i < 64 * 16; i += 256) Ws[i] = W[i];
    long long row0 = (long long)blockIdx.x * 16;
    ushort4 u4 = ((const ushort4*)(h + row0 * 64))[t];
    int lr = t >> 4, lc = (t & 15) * 4;
    xs[lr][lc + 0] = bf16dec(u4.x);
    xs[lr][lc + 1] = bf16dec(u4.y);
    xs[lr][lc + 2] = bf16dec(u4.z);
    xs[lr][lc + 3] = bf16dec(u4.w);
    __syncthreads();
    int r = t >> 4, c = t & 15;
    float acc = 0.f;
#pragma unroll
    for (int k = 0; k < 64; ++k) acc += xs[r][k] * Ws[k * 16 + c];
    h2[(row0 + r) * 16 + c] = bf16enc(dinv[row0 + r] * acc);
}

// ------- CSR aggregation, 64 feats (bf16 h, 2-wide): wave per node --------------
// 32 lanes cover a 128B row (uint = 2 bf16 feats); half-waves take even/odd edges.
__global__ __launch_bounds__(256) void k_agg64(const int* __restrict__ rowstart,
                                               const int* __restrict__ counts,
                                               const unsigned int* __restrict__ srcs,
                                               const unsigned int* __restrict__ hb2,
                                               const float* __restrict__ dinv,
                                               const float* __restrict__ b,
                                               unsigned short* __restrict__ out, int n) {
    int d = (blockIdx.x * 256 + threadIdx.x) >> 6;
    if (d >= n) return;
    int lane = threadIdx.x & 63;
    int half = lane >> 5;     // 0: even edges, 1: odd edges
    int fl = lane & 31;       // feature-pair index (features 2fl, 2fl+1)
    float ax = 0.f, ay = 0.f;
    if (half == 0) {          // self-loop counted once
        unsigned int u = hb2[(long long)d * 32 + fl];
        ax = bf16lo(u); ay = bf16hi(u);
    }
    int start = rowstart[d];
    int cnt = counts[d];
    int k = 0;
    for (; k + 8 <= cnt; k += 8) {
        unsigned int s0 = srcs[start + k + half];
        unsigned int s1 = srcs[start + k + 2 + half];
        unsigned int s2 = srcs[start + k + 4 + half];
        unsigned int s3 = srcs[start + k + 6 + half];
        unsigned int u0 = hb2[(long long)s0 * 32 + fl];
        unsigned int u1 = hb2[(long long)s1 * 32 + fl];
        unsigned int u2 = hb2[(long long)s2 * 32 + fl];
        unsigned int u3 = hb2[(long long)s3 * 32 + fl];
        ax += bf16lo(u0); ay += bf16hi(u0);
        ax += bf16lo(u1); ay += bf16hi(u1);
        ax += bf16lo(u2); ay += bf16hi(u2);
        ax += bf16lo(u3); ay += bf16hi(u3);
    }
    for (; k < cnt; k += 2) {
        int idx = k + half;
        unsigned int u0 = 0;
        if (idx < cnt) u0 = hb2[(long long)srcs[start + idx] * 32 + fl];
        ax += bf16lo(u0); ay += bf16hi(u0);
    }
    // combine even/odd halves (lane <-> lane^32 holds same fl)
    ax += __shfl_xor(ax, 32);
    ay += __shfl_xor(ay, 32);
    float di = dinv[d];
    float2 bb = ((const float2*)b)[fl];
    float ox = fmaxf(di * ax + bb.x, 0.f);
    float oy = fmaxf(di * ay + bb.y, 0.f);
    if (half == 0) {
        unsigned int pk = (unsigned int)bf16enc(ox) | ((unsigned int)bf16enc(oy) << 16);
        ((unsigned int*)(out + (long long)d * 64))[fl] = pk;
    }
}

// ------- CSR aggregation, 16 feats (bf16 h) + fused log_softmax ----------------
__global__ __launch_bounds__(256) void k_agg16(const int* __restrict__ rowstart,
                                               const int* __restrict__ counts,
                                               const unsigned int* __restrict__ srcs,
                                               const unsigned short* __restrict__ hb,
                                               const float* __restrict__ dinv,
                                               const float* __restrict__ b,
                                               float* __restrict__ out, int n) {
    int g = (blockIdx.x * 256 + threadIdx.x) >> 4;
    if (g >= n) return;
    int f = threadIdx.x & 15;
    long long rb = (long long)g * 16;
    float acc = bf16dec(hb[rb + f]);
    int start = rowstart[g];
    int cnt = counts[g];
    int k = 0;
    for (; k + 8 <= cnt; k += 8) {
        unsigned int s0 = srcs[start + k];
        unsigned int s1 = srcs[start + k + 1];
        unsigned int s2 = srcs[start + k + 2];
        unsigned int s3 = srcs[start + k + 3];
        unsigned int s4 = srcs[start + k + 4];
        unsigned int s5 = srcs[start + k + 5];
        unsigned int s6 = srcs[start + k + 6];
        unsigned int s7 = srcs[start + k + 7];
        unsigned short u0 = hb[(long long)s0 * 16 + f];
        unsigned short u1 = hb[(long long)s1 * 16 + f];
        unsigned short u2 = hb[(long long)s2 * 16 + f];
        unsigned short u3 = hb[(long long)s3 * 16 + f];
        unsigned short u4 = hb[(long long)s4 * 16 + f];
        unsigned short u5 = hb[(long long)s5 * 16 + f];
        unsigned short u6 = hb[(long long)s6 * 16 + f];
        unsigned short u7 = hb[(long long)s7 * 16 + f];
        acc += bf16dec(u0); acc += bf16dec(u1); acc += bf16dec(u2); acc += bf16dec(u3);
        acc += bf16dec(u4); acc += bf16dec(u5); acc += bf16dec(u6); acc += bf16dec(u7);
    }
    for (; k < cnt; ++k) acc += bf16dec(hb[(long long)srcs[start + k] * 16 + f]);
    float v = dinv[g] * acc + b[f];
    float m = v;
#pragma unroll
    for (int o = 8; o >= 1; o >>= 1) m = fmaxf(m, __shfl_xor(m, o, 16));
    float ex = __expf(v - m);
#pragma unroll
    for (int o = 8; o >= 1; o >>= 1) ex += __shfl_xor(ex, o, 16);
    out[rb + f] = (v - m) - __logf(ex);
}

extern "C" void kernel_launch(void* const* d_in, const int* in_sizes, int n_in,
                              void* d_out, int out_size, void* d_ws, size_t ws_size,
                              hipStream_t stream) {
    const float* x  = (const float*)d_in[0];
    const void*  ei = d_in[1];
    const float* W1 = (const float*)d_in[2];
    const float* b1 = (const float*)d_in[3];
    const float* W2 = (const float*)d_in[4];
    const float* b2 = (const float*)d_in[5];

    long long dh  = in_sizes[3];                 // 64
    long long din = in_sizes[2] / dh;            // 64
    long long n   = in_sizes[0] / din;           // 50000
    long long E   = (long long)in_sizes[1] / 2;  // 1.6M
    int nbuckets  = (int)((n + BNODES - 1) >> BSHIFT);  // 782

    // slice size: 512 threads x ~16 edges; keep block count <= 256 (k_scanB width)
    long long epb = 8192;
    while ((E + epb - 1) / epb > 256) epb <<= 1;
    int nblk = (int)((E + epb - 1) / epb);       // 196 for E=1.6M

    char* ws = (char*)d_ws;
    auto alloc = [&](size_t bytes) { void* p = ws; ws += (bytes + 255) & ~255ULL; return p; };
    int*   totals   = (int*)alloc(nbuckets * 4);
    int*   base     = (int*)alloc(nbuckets * 4);
    int*   rowstart = (int*)alloc(n * 4);
    int*   counts   = (int*)alloc(n * 4);
    float* dinv     = (float*)alloc(n * 4);
    int*   partial  = (int*)alloc((size_t)nbuckets * nblk * 4);
    unsigned int* keys = (unsigned int*)alloc(E * 4);
    unsigned short* h1b  = (unsigned short*)alloc(n * 64 * 2);
    unsigned short* out1 = (unsigned short*)alloc(n * 64 * 2);
    unsigned short* h2b  = (unsigned short*)alloc(n * 16 * 2);
    // out1 written only after sortdeg completes; before then its space doubles
    // as the (statistically never used) big-bucket sort scratch (E*4 <= n*64*2).
    unsigned int* sort_scratch = (unsigned int*)out1;

    float* out = (float*)d_out;

    // binning: hist -> per-bucket block scan -> bucket scan -> place (no global atomics)
    k_hist<<<nblk, 512, 0, stream>>>(ei, n, E, epb, nbuckets, nblk, partial);
    k_scanB<<<nbuckets, 256, 0, stream>>>(partial, nblk, totals);
    k_scan<<<1, 1024, 0, stream>>>(totals, nbuckets, base);
    k_place<<<nblk, 512, 0, stream>>>(ei, n, E, epb, nbuckets, nblk, base, partial, keys);
    k_sortdeg<<<nbuckets, 256, 0, stream>>>(keys, base, totals, rowstart, counts,
                                            dinv, (int)n, sort_scratch);

    // layer 1
    k_gemm1<<<(int)(n / 16), 256, 0, stream>>>(x, W1, dinv, h1b);
    k_agg64<<<(int)((n * 64 + 255) / 256), 256, 0, stream>>>(
        rowstart, counts, keys, (const unsigned int*)h1b, dinv, b1, out1, (int)n);

    // layer 2
    k_gemm2<<<(int)(n / 16), 256, 0, stream>>>(out1, W2, dinv, h2b);
    k_agg16<<<(int)((n * 16 + 255) / 256), 256, 0, stream>>>(
        rowstart, counts, keys, h2b, dinv, b2, out, (int)n);
}